// Round 1
// baseline (703.991 us; speedup 1.0000x reference)
//
#include <hip/hip_runtime.h>

typedef __attribute__((ext_vector_type(8))) short short8v;
typedef __attribute__((ext_vector_type(4))) float f32x4;
typedef __attribute__((ext_vector_type(4))) unsigned int uint4v;

#define GLOBAL_AS(p) ((const __attribute__((address_space(1))) void*)(p))
#define LDS_AS(p)    ((__attribute__((address_space(3))) void*)(p))

__device__ __forceinline__ unsigned short f2bf(float f) {
  unsigned int u = __builtin_bit_cast(unsigned int, f);
  u += 0x7fffu + ((u >> 16) & 1u);
  return (unsigned short)(u >> 16);
}
__device__ __forceinline__ float bf2f(unsigned short u) {
  unsigned int x = ((unsigned int)u) << 16;
  return __builtin_bit_cast(float, x);
}

// ---------------------------------------------------------------------------
// Transpose fp32 [K,N] -> bf16 [N,K]
__global__ __launch_bounds__(256) void transpose_to_bf16(
    const float* __restrict__ src, unsigned short* __restrict__ dst,
    int K, int N, int ntx) {
  __shared__ float tile[32][33];
  const int bx = blockIdx.x % ntx;  // n tile
  const int by = blockIdx.x / ntx;  // k tile
  const int tx = threadIdx.x & 31, ty = threadIdx.x >> 5;
  const int k0 = by * 32, n0 = bx * 32;
#pragma unroll
  for (int i = 0; i < 32; i += 8)
    tile[ty + i][tx] = src[(size_t)(k0 + ty + i) * N + n0 + tx];
  __syncthreads();
#pragma unroll
  for (int i = 0; i < 32; i += 8)
    dst[(size_t)(n0 + ty + i) * K + k0 + tx] = f2bf(tile[tx][ty + i]);
}

// fp32 -> bf16, 8 elements/thread, exact-sized grid
__global__ __launch_bounds__(256) void cvt_f32_bf16(
    const float* __restrict__ s, unsigned short* __restrict__ d) {
  size_t i = ((size_t)blockIdx.x * 256 + threadIdx.x) * 8;
  f32x4 v0 = *(const f32x4*)(s + i);
  f32x4 v1 = *(const f32x4*)(s + i + 4);
  union U8 { uint4v v; unsigned short us[8]; } o;
  o.us[0] = f2bf(v0.x); o.us[1] = f2bf(v0.y); o.us[2] = f2bf(v0.z); o.us[3] = f2bf(v0.w);
  o.us[4] = f2bf(v1.x); o.us[5] = f2bf(v1.y); o.us[6] = f2bf(v1.z); o.us[7] = f2bf(v1.w);
  *(uint4v*)(d + i) = o.v;
}

__global__ __launch_bounds__(256) void copy_f32(
    const float* __restrict__ s, float* __restrict__ d, int n) {
  int i = blockIdx.x * 256 + threadIdx.x;
  if (i < n) d[i] = s[i];
}

// ---------------------------------------------------------------------------
// GEMM: A[M,K] bf16 row-major (lda), Bt[N,K] bf16 row-major (ldb),
// C[M,N] (+bias[n]) as bf16 or fp32 (ldc). 128x128 tile, BK=64, 4 waves.
// global_load_lds(16B) with pre-swizzled global source; ds_read_b128 frags.
#define BM 128
#define BN 128
#define BK 64

template <int OUT_BF16>
__global__ __launch_bounds__(256) void gemm_bt(
    const unsigned short* __restrict__ A, int lda,
    const unsigned short* __restrict__ Bt, int ldb,
    const float* __restrict__ bias, void* __restrict__ Cp, int ldc,
    int K, int ntn) {
  __shared__ unsigned short Als[BM * BK];
  __shared__ unsigned short Bls[BN * BK];
  const int t = threadIdx.x;
  const int lane = t & 63, wave = t >> 6;
  const int bm = (blockIdx.x / ntn) * BM;
  const int bn = (blockIdx.x % ntn) * BN;
  const int wm = (wave >> 1) * 64, wn = (wave & 1) * 64;
  const int g = lane >> 4, r = lane & 15, swz = r & 7;
  const int srow = t >> 3, sj = t & 7, sswz = srow & 7;

  f32x4 acc[4][4];
#pragma unroll
  for (int i = 0; i < 4; ++i)
#pragma unroll
    for (int j = 0; j < 4; ++j) acc[i][j] = (f32x4){0.f, 0.f, 0.f, 0.f};

  // per-thread staging source (swizzled chunk) and per-wave linear LDS dest
  const size_t abase = (size_t)(bm + srow) * lda + (size_t)((sj ^ sswz) << 3);
  const size_t bbase = (size_t)(bn + srow) * ldb + (size_t)((sj ^ sswz) << 3);
  unsigned short* ldsA = &Als[wave * 512];
  unsigned short* ldsB = &Bls[wave * 512];

  for (int k0 = 0; k0 < K; k0 += BK) {
#pragma unroll
    for (int c = 0; c < 4; ++c) {
      __builtin_amdgcn_global_load_lds(GLOBAL_AS(A + abase + (size_t)c * 32 * lda + k0),
                                       LDS_AS(ldsA + c * 2048), 16, 0, 0);
      __builtin_amdgcn_global_load_lds(GLOBAL_AS(Bt + bbase + (size_t)c * 32 * ldb + k0),
                                       LDS_AS(ldsB + c * 2048), 16, 0, 0);
    }
    __syncthreads();
#pragma unroll
    for (int ks = 0; ks < 2; ++ks) {
      short8v af[4], bf[4];
#pragma unroll
      for (int i = 0; i < 4; ++i) {
        const int koff = ((((ks << 2) + g) ^ swz) << 3);
        af[i] = *(const short8v*)&Als[(wm + i * 16 + r) * BK + koff];
        bf[i] = *(const short8v*)&Bls[(wn + i * 16 + r) * BK + koff];
      }
#pragma unroll
      for (int mi = 0; mi < 4; ++mi)
#pragma unroll
        for (int ni = 0; ni < 4; ++ni)
          acc[mi][ni] = __builtin_amdgcn_mfma_f32_16x16x32_bf16(
              af[mi], bf[ni], acc[mi][ni], 0, 0, 0);
    }
    __syncthreads();
  }

#pragma unroll
  for (int ni = 0; ni < 4; ++ni) {
    const int col = bn + wn + ni * 16 + r;
    const float bv = bias[col];
#pragma unroll
    for (int mi = 0; mi < 4; ++mi) {
      const int row0 = bm + wm + mi * 16 + (g << 2);
#pragma unroll
      for (int j = 0; j < 4; ++j) {
        float v = acc[mi][ni][j] + bv;
        if (OUT_BF16)
          ((unsigned short*)Cp)[(size_t)(row0 + j) * ldc + col] = f2bf(v);
        else
          ((float*)Cp)[(size_t)(row0 + j) * ldc + col] = v;
      }
    }
  }
}

// ---------------------------------------------------------------------------
// Per-token attention: q from out1[:,1024:3072] (ld 3072), k/v from kv
// [16384,4096] (k cols 0..2047, v cols 2048..4095). fp32 in LDS.
__global__ __launch_bounds__(256) void attn_kernel(
    const unsigned short* __restrict__ out1, const unsigned short* __restrict__ kv,
    unsigned short* __restrict__ aout) {
  const int s = blockIdx.x;
  const int t = threadIdx.x;
  __shared__ float qs[16 * 132], ks2[16 * 132], vs[16 * 132];
  __shared__ float attn[256];
  const int h = t >> 4, d0 = (t & 15) * 8;

  union U8 { uint4v v; unsigned short us[8]; };
  U8 qv, kv8, vv;
  qv.v = *(const uint4v*)(out1 + (size_t)s * 3072 + 1024 + t * 8);
  kv8.v = *(const uint4v*)(kv + (size_t)s * 4096 + t * 8);
  vv.v = *(const uint4v*)(kv + (size_t)s * 4096 + 2048 + t * 8);
#pragma unroll
  for (int j = 0; j < 8; ++j) {
    qs[h * 132 + d0 + j] = bf2f(qv.us[j]);
    ks2[h * 132 + d0 + j] = bf2f(kv8.us[j]);
    vs[h * 132 + d0 + j] = bf2f(vv.us[j]);
  }
  __syncthreads();

  // sim[h][g], thread t -> (h = t>>4, g = t&15)
  const int gg0 = t & 15;
  const f32x4* qrow = (const f32x4*)&qs[h * 132];
  const f32x4* krow = (const f32x4*)&ks2[gg0 * 132];
  float acc = 0.f;
#pragma unroll
  for (int dd = 0; dd < 32; ++dd) {
    f32x4 a4 = qrow[dd], b4 = krow[dd];
    acc += a4.x * b4.x + a4.y * b4.y + a4.z * b4.z + a4.w * b4.w;
  }
  acc *= 0.08838834764831845f;  // D^-0.5
  float mx = acc;
#pragma unroll
  for (int o = 8; o; o >>= 1) mx = fmaxf(mx, __shfl_xor(mx, o));
  float e = __expf(acc - mx);
  float sm = e;
#pragma unroll
  for (int o = 8; o; o >>= 1) sm += __shfl_xor(sm, o);
  attn[t] = e / sm;
  __syncthreads();

  // out[h][d] = sum_g attn[h][g] * v[g][d]; thread t -> 8 outputs at (h, d0)
  f32x4 o0 = (f32x4){0.f, 0.f, 0.f, 0.f}, o1 = (f32x4){0.f, 0.f, 0.f, 0.f};
#pragma unroll
  for (int gg = 0; gg < 16; ++gg) {
    const float a = attn[(h << 4) + gg];
    f32x4 v0 = *(const f32x4*)&vs[gg * 132 + d0];
    f32x4 v1 = *(const f32x4*)&vs[gg * 132 + d0 + 4];
    o0 += v0 * a;
    o1 += v1 * a;
  }
  U8 ov;
  ov.us[0] = f2bf(o0.x); ov.us[1] = f2bf(o0.y); ov.us[2] = f2bf(o0.z); ov.us[3] = f2bf(o0.w);
  ov.us[4] = f2bf(o1.x); ov.us[5] = f2bf(o1.y); ov.us[6] = f2bf(o1.z); ov.us[7] = f2bf(o1.w);
  *(uint4v*)(aout + (size_t)s * 2048 + t * 8) = ov.v;
}

// ---------------------------------------------------------------------------
extern "C" void kernel_launch(void* const* d_in, const int* in_sizes, int n_in,
                              void* d_out, int out_size, void* d_ws, size_t ws_size,
                              hipStream_t stream) {
  (void)in_sizes; (void)n_in; (void)out_size; (void)ws_size;
  const float* x    = (const float*)d_in[0];
  const float* Wd_k = (const float*)d_in[1];
  const float* bd_k = (const float*)d_in[2];
  const float* Wu_k = (const float*)d_in[3];
  const float* bu_k = (const float*)d_in[4];
  const float* Wd_v = (const float*)d_in[5];
  const float* bd_v = (const float*)d_in[6];
  const float* Wu_v = (const float*)d_in[7];
  const float* bu_v = (const float*)d_in[8];
  const float* Wq   = (const float*)d_in[9];
  const float* bq   = (const float*)d_in[10];
  const float* Wo   = (const float*)d_in[11];
  const float* bo   = (const float*)d_in[12];

  char* ws = (char*)d_ws;
  // byte offsets
  unsigned short* w1t  = (unsigned short*)(ws);                      // [3072][2048] bf16
  unsigned short* w2t  = (unsigned short*)(ws + 12582912);           // [4096][512]  bf16
  unsigned short* w3t  = (unsigned short*)(ws + 16777216);           // [2048][2048] bf16
  float*          b1   = (float*)(ws + 25165824);                    // [3072]
  float*          b2   = (float*)(ws + 25178112);                    // [4096]
  unsigned short* xb   = (unsigned short*)(ws + 25194496);           // [16384][2048] bf16
  unsigned short* out1 = (unsigned short*)(ws + 92303360);           // [16384][3072] bf16
  unsigned short* kvb  = (unsigned short*)(ws + 192966656);          // [16384][4096] bf16
  unsigned short* attO = xb;  // reuse xb region after GEMM1: [16384][2048] bf16

  dim3 blk(256);

  // weight transposes (fp32 [K,N] -> bf16 [N,K])
  transpose_to_bf16<<<dim3(16 * 64), blk, 0, stream>>>(Wd_k, w1t,               2048, 512, 16);
  transpose_to_bf16<<<dim3(16 * 64), blk, 0, stream>>>(Wd_v, w1t + 512 * 2048,  2048, 512, 16);
  transpose_to_bf16<<<dim3(64 * 64), blk, 0, stream>>>(Wq,   w1t + 1024 * 2048, 2048, 2048, 64);
  transpose_to_bf16<<<dim3(64 * 16), blk, 0, stream>>>(Wu_k, w2t,               512, 2048, 64);
  transpose_to_bf16<<<dim3(64 * 16), blk, 0, stream>>>(Wu_v, w2t + 2048 * 512,  512, 2048, 64);
  transpose_to_bf16<<<dim3(64 * 64), blk, 0, stream>>>(Wo,   w3t,               2048, 2048, 64);

  // bias concat
  copy_f32<<<dim3(2), blk, 0, stream>>>(bd_k, b1, 512);
  copy_f32<<<dim3(2), blk, 0, stream>>>(bd_v, b1 + 512, 512);
  copy_f32<<<dim3(8), blk, 0, stream>>>(bq,   b1 + 1024, 2048);
  copy_f32<<<dim3(8), blk, 0, stream>>>(bu_k, b2, 2048);
  copy_f32<<<dim3(8), blk, 0, stream>>>(bu_v, b2 + 2048, 2048);

  // x -> bf16 (33,554,432 elems / 8 / 256 = 16384 blocks)
  cvt_f32_bf16<<<dim3(16384), blk, 0, stream>>>(x, xb);

  // GEMM1: [16384,2048] @ [2048,3072] -> out1 bf16 (cache_k|cache_v|q)
  gemm_bt<1><<<dim3(128 * 24), blk, 0, stream>>>(xb, 2048, w1t, 2048, b1, out1, 3072, 2048, 24);

  // GEMM2: k = cache_k @ Wu_k -> kv[:,0:2048]; v = cache_v @ Wu_v -> kv[:,2048:4096]
  gemm_bt<1><<<dim3(128 * 16), blk, 0, stream>>>(out1, 3072, w2t, 512, b2, kvb, 4096, 512, 16);
  gemm_bt<1><<<dim3(128 * 16), blk, 0, stream>>>(out1 + 512, 3072, w2t + 2048 * 512, 512,
                                                 b2 + 2048, kvb + 2048, 4096, 512, 16);

  // per-token attention -> attO bf16 [16384,2048]
  attn_kernel<<<dim3(16384), blk, 0, stream>>>(out1, kvb, attO);

  // GEMM3: attO @ Wo + bo -> d_out fp32
  gemm_bt<0><<<dim3(128 * 16), blk, 0, stream>>>(attO, 2048, w3t, 2048, bo, (float*)d_out,
                                                 2048, 2048, 16);
}

// Round 2
// 607.310 us; speedup vs baseline: 1.1592x; 1.1592x over previous
//
#include <hip/hip_runtime.h>

typedef __attribute__((ext_vector_type(8))) short short8v;
typedef __attribute__((ext_vector_type(4))) float f32x4;
typedef __attribute__((ext_vector_type(4))) unsigned int uint4v;

#define GLOBAL_AS(p) ((const __attribute__((address_space(1))) void*)(p))
#define LDS_AS(p)    ((__attribute__((address_space(3))) void*)(p))
#define WAITV(n) asm volatile("s_waitcnt vmcnt(" #n ")" ::: "memory")
#define BARRIER() __builtin_amdgcn_s_barrier()
#define SCHED0() __builtin_amdgcn_sched_barrier(0)

__device__ __forceinline__ unsigned short f2bf(float f) {
  unsigned int u = __builtin_bit_cast(unsigned int, f);
  u += 0x7fffu + ((u >> 16) & 1u);
  return (unsigned short)(u >> 16);
}
__device__ __forceinline__ float bf2f(unsigned short u) {
  unsigned int x = ((unsigned int)u) << 16;
  return __builtin_bit_cast(float, x);
}

// ---------------------------------------------------------------------------
// Transpose fp32 [K,N] -> bf16 [N,K]
__global__ __launch_bounds__(256) void transpose_to_bf16(
    const float* __restrict__ src, unsigned short* __restrict__ dst,
    int K, int N, int ntx) {
  __shared__ float tile[32][33];
  const int bx = blockIdx.x % ntx;
  const int by = blockIdx.x / ntx;
  const int tx = threadIdx.x & 31, ty = threadIdx.x >> 5;
  const int k0 = by * 32, n0 = bx * 32;
#pragma unroll
  for (int i = 0; i < 32; i += 8)
    tile[ty + i][tx] = src[(size_t)(k0 + ty + i) * N + n0 + tx];
  __syncthreads();
#pragma unroll
  for (int i = 0; i < 32; i += 8)
    dst[(size_t)(n0 + ty + i) * K + k0 + tx] = f2bf(tile[tx][ty + i]);
}

// fp32 -> bf16, 8 elements/thread
__global__ __launch_bounds__(256) void cvt_f32_bf16(
    const float* __restrict__ s, unsigned short* __restrict__ d) {
  size_t i = ((size_t)blockIdx.x * 256 + threadIdx.x) * 8;
  f32x4 v0 = *(const f32x4*)(s + i);
  f32x4 v1 = *(const f32x4*)(s + i + 4);
  union U8 { uint4v v; unsigned short us[8]; } o;
  o.us[0] = f2bf(v0.x); o.us[1] = f2bf(v0.y); o.us[2] = f2bf(v0.z); o.us[3] = f2bf(v0.w);
  o.us[4] = f2bf(v1.x); o.us[5] = f2bf(v1.y); o.us[6] = f2bf(v1.z); o.us[7] = f2bf(v1.w);
  *(uint4v*)(d + i) = o.v;
}

// combined bias concat: b1 = [bd_k|bd_v|bq] (3072), b2 = [bu_k|bu_v] (4096)
__global__ __launch_bounds__(256) void fill_bias(
    const float* __restrict__ bd_k, const float* __restrict__ bd_v,
    const float* __restrict__ bq, const float* __restrict__ bu_k,
    const float* __restrict__ bu_v, float* __restrict__ b1, float* __restrict__ b2) {
  int i = blockIdx.x * 256 + threadIdx.x;  // grid covers 7168
  if (i < 512) b1[i] = bd_k[i];
  else if (i < 1024) b1[i] = bd_v[i - 512];
  else if (i < 3072) b1[i] = bq[i - 1024];
  else if (i < 5120) b2[i - 3072] = bu_k[i - 3072];
  else if (i < 7168) b2[i - 3072] = bu_v[i - 5120];
}

// ---------------------------------------------------------------------------
// GEMM: A[M,K] bf16 (lda), Bt[N,K] bf16 (ldb), C[M,N]+bias as bf16/fp32.
// 256x256 tile, BK=64, 8 waves (2Mx4N), per-wave 128x64. Double-buffered LDS
// (128 KiB), counted vmcnt(8) prefetch (tile t+1 in flight across barrier),
// XOR-swizzled LDS via pre-swizzled global source (linear gload_lds dest).
// nsplit_col/acol_off: blocks with bn>=nsplit read A shifted by acol_off
// (fuses the two latent up-projections into one launch).
template <int OUT_BF16>
__global__ __launch_bounds__(512, 2) void gemm_bt(
    const unsigned short* __restrict__ A, int lda, int nsplit_col, int acol_off,
    const unsigned short* __restrict__ Bt, int ldb,
    const float* __restrict__ bias, void* __restrict__ Cp, int ldc,
    int K, int ntn) {
  __shared__ unsigned short lds[2][2][256 * 64];  // [buf][A|B][row*64+col]
  const int t = threadIdx.x;
  const int lane = t & 63, wave = t >> 6;

  // bijective XCD swizzle (grid always a multiple of 8 here)
  const int q = gridDim.x >> 3;
  const int bid = (blockIdx.x & 7) * q + (blockIdx.x >> 3);
  const int bm = (bid / ntn) * 256;
  const int bn = (bid % ntn) * 256;
  const unsigned short* Ab = A + (bn >= nsplit_col ? acol_off : 0);

  const int wr = wave >> 2, wc = wave & 3;
  const int g = lane >> 4, r = lane & 15;
  const int srow = t >> 3, sj = t & 7;
  const int jsrc = sj ^ (srow & 7);  // inverse-swizzled source chunk
  const int NT = K >> 6;

  f32x4 acc[8][4];
#pragma unroll
  for (int i = 0; i < 8; ++i)
#pragma unroll
    for (int j = 0; j < 4; ++j) acc[i][j] = (f32x4){0.f, 0.f, 0.f, 0.f};

  const unsigned short* aptr = Ab + (size_t)(bm + srow) * lda + (jsrc << 3);
  const unsigned short* bptr = Bt + (size_t)(bn + srow) * ldb + (jsrc << 3);
  const int sbase = wave * 512;  // elems: wave-uniform LDS stage base

  auto stage = [&](int kt, int buf) {
    const unsigned short* ak = aptr + kt * 64;
    const unsigned short* bk = bptr + kt * 64;
    unsigned short* la = &lds[buf][0][sbase];
    unsigned short* lb = &lds[buf][1][sbase];
#pragma unroll
    for (int c = 0; c < 4; ++c) {
      __builtin_amdgcn_global_load_lds(GLOBAL_AS(ak + (size_t)c * 64 * lda),
                                       LDS_AS(la + c * 4096), 16, 0, 0);
      __builtin_amdgcn_global_load_lds(GLOBAL_AS(bk + (size_t)c * 64 * ldb),
                                       LDS_AS(lb + c * 4096), 16, 0, 0);
    }
  };

  stage(0, 0);

  const int arow = wr * 128 + r;
  const int brow = wc * 64 + r;
  const int swz = r & 7;

  for (int kt = 0; kt < NT; ++kt) {
    const int cur = kt & 1;
    if (kt + 1 < NT) {
      stage(kt + 1, cur ^ 1);
      SCHED0();
      WAITV(8);   // tile kt resident; tile kt+1's 8 loads stay in flight
    } else {
      WAITV(0);
    }
    BARRIER();
    SCHED0();
    const unsigned short* la = lds[cur][0];
    const unsigned short* lb = lds[cur][1];
#pragma unroll
    for (int ks = 0; ks < 2; ++ks) {
      const int c16 = (((ks << 2) + g) ^ swz) << 3;
      short8v bfr[4], afr[8];
#pragma unroll
      for (int ni = 0; ni < 4; ++ni)
        bfr[ni] = *(const short8v*)&lb[(brow + ni * 16) * 64 + c16];
#pragma unroll
      for (int mi = 0; mi < 8; ++mi)
        afr[mi] = *(const short8v*)&la[(arow + mi * 16) * 64 + c16];
      __builtin_amdgcn_s_setprio(1);
#pragma unroll
      for (int mi = 0; mi < 8; ++mi)
#pragma unroll
        for (int ni = 0; ni < 4; ++ni)
          acc[mi][ni] = __builtin_amdgcn_mfma_f32_16x16x32_bf16(
              afr[mi], bfr[ni], acc[mi][ni], 0, 0, 0);
      __builtin_amdgcn_s_setprio(0);
    }
    SCHED0();
    BARRIER();   // all reads of lds[cur] done before next stage overwrites it
    SCHED0();
  }

#pragma unroll
  for (int ni = 0; ni < 4; ++ni) {
    const int col = bn + wc * 64 + ni * 16 + r;
    const float bv = bias[col];
#pragma unroll
    for (int mi = 0; mi < 8; ++mi) {
      const int row0 = bm + wr * 128 + mi * 16 + (g << 2);
#pragma unroll
      for (int j = 0; j < 4; ++j) {
        float v = acc[mi][ni][j] + bv;
        if (OUT_BF16)
          ((unsigned short*)Cp)[(size_t)(row0 + j) * ldc + col] = f2bf(v);
        else
          ((float*)Cp)[(size_t)(row0 + j) * ldc + col] = v;
      }
    }
  }
}

// ---------------------------------------------------------------------------
// Per-token head-vs-head attention (16x16 per token), fp32 math.
__global__ __launch_bounds__(256) void attn_kernel(
    const unsigned short* __restrict__ out1, const unsigned short* __restrict__ kv,
    unsigned short* __restrict__ aout) {
  const int s = blockIdx.x;
  const int t = threadIdx.x;
  __shared__ float qs[16 * 132], ks2[16 * 132], vs[16 * 132];
  __shared__ float attn[256];
  const int h = t >> 4, d0 = (t & 15) * 8;

  union U8 { uint4v v; unsigned short us[8]; };
  U8 qv, kv8, vv;
  qv.v = *(const uint4v*)(out1 + (size_t)s * 3072 + 1024 + t * 8);
  kv8.v = *(const uint4v*)(kv + (size_t)s * 4096 + t * 8);
  vv.v = *(const uint4v*)(kv + (size_t)s * 4096 + 2048 + t * 8);
#pragma unroll
  for (int j = 0; j < 8; ++j) {
    qs[h * 132 + d0 + j] = bf2f(qv.us[j]);
    ks2[h * 132 + d0 + j] = bf2f(kv8.us[j]);
    vs[h * 132 + d0 + j] = bf2f(vv.us[j]);
  }
  __syncthreads();

  const int gg0 = t & 15;
  const f32x4* qrow = (const f32x4*)&qs[h * 132];
  const f32x4* krow = (const f32x4*)&ks2[gg0 * 132];
  float acc = 0.f;
#pragma unroll
  for (int dd = 0; dd < 32; ++dd) {
    f32x4 a4 = qrow[dd], b4 = krow[dd];
    acc += a4.x * b4.x + a4.y * b4.y + a4.z * b4.z + a4.w * b4.w;
  }
  acc *= 0.08838834764831845f;
  float mx = acc;
#pragma unroll
  for (int o = 8; o; o >>= 1) mx = fmaxf(mx, __shfl_xor(mx, o));
  float e = __expf(acc - mx);
  float sm = e;
#pragma unroll
  for (int o = 8; o; o >>= 1) sm += __shfl_xor(sm, o);
  attn[t] = e / sm;
  __syncthreads();

  f32x4 o0 = (f32x4){0.f, 0.f, 0.f, 0.f}, o1 = (f32x4){0.f, 0.f, 0.f, 0.f};
#pragma unroll
  for (int gg = 0; gg < 16; ++gg) {
    const float a = attn[(h << 4) + gg];
    f32x4 v0 = *(const f32x4*)&vs[gg * 132 + d0];
    f32x4 v1 = *(const f32x4*)&vs[gg * 132 + d0 + 4];
    o0 += v0 * a;
    o1 += v1 * a;
  }
  U8 ov;
  ov.us[0] = f2bf(o0.x); ov.us[1] = f2bf(o0.y); ov.us[2] = f2bf(o0.z); ov.us[3] = f2bf(o0.w);
  ov.us[4] = f2bf(o1.x); ov.us[5] = f2bf(o1.y); ov.us[6] = f2bf(o1.z); ov.us[7] = f2bf(o1.w);
  *(uint4v*)(aout + (size_t)s * 2048 + t * 8) = ov.v;
}

// ---------------------------------------------------------------------------
extern "C" void kernel_launch(void* const* d_in, const int* in_sizes, int n_in,
                              void* d_out, int out_size, void* d_ws, size_t ws_size,
                              hipStream_t stream) {
  (void)in_sizes; (void)n_in; (void)out_size; (void)ws_size;
  const float* x    = (const float*)d_in[0];
  const float* Wd_k = (const float*)d_in[1];
  const float* bd_k = (const float*)d_in[2];
  const float* Wu_k = (const float*)d_in[3];
  const float* bu_k = (const float*)d_in[4];
  const float* Wd_v = (const float*)d_in[5];
  const float* bd_v = (const float*)d_in[6];
  const float* Wu_v = (const float*)d_in[7];
  const float* bu_v = (const float*)d_in[8];
  const float* Wq   = (const float*)d_in[9];
  const float* bq   = (const float*)d_in[10];
  const float* Wo   = (const float*)d_in[11];
  const float* bo   = (const float*)d_in[12];

  char* ws = (char*)d_ws;
  unsigned short* w1t  = (unsigned short*)(ws);             // [3072][2048] bf16
  unsigned short* w2t  = (unsigned short*)(ws + 12582912);  // [4096][512]  bf16
  unsigned short* w3t  = (unsigned short*)(ws + 16777216);  // [2048][2048] bf16
  float*          b1   = (float*)(ws + 25165824);           // [3072]
  float*          b2   = (float*)(ws + 25178112);           // [4096]
  unsigned short* xb   = (unsigned short*)(ws + 25194496);  // [16384][2048] bf16
  unsigned short* out1 = (unsigned short*)(ws + 92303360);  // [16384][3072] bf16
  unsigned short* kvb  = (unsigned short*)(ws + 192966656); // [16384][4096] bf16
  unsigned short* attO = xb;  // reuse xb after GEMM1

  dim3 blk(256);

  transpose_to_bf16<<<dim3(16 * 64), blk, 0, stream>>>(Wd_k, w1t,               2048, 512, 16);
  transpose_to_bf16<<<dim3(16 * 64), blk, 0, stream>>>(Wd_v, w1t + 512 * 2048,  2048, 512, 16);
  transpose_to_bf16<<<dim3(64 * 64), blk, 0, stream>>>(Wq,   w1t + 1024 * 2048, 2048, 2048, 64);
  transpose_to_bf16<<<dim3(64 * 16), blk, 0, stream>>>(Wu_k, w2t,               512, 2048, 64);
  transpose_to_bf16<<<dim3(64 * 16), blk, 0, stream>>>(Wu_v, w2t + 2048 * 512,  512, 2048, 64);
  transpose_to_bf16<<<dim3(64 * 64), blk, 0, stream>>>(Wo,   w3t,               2048, 2048, 64);

  fill_bias<<<dim3(28), blk, 0, stream>>>(bd_k, bd_v, bq, bu_k, bu_v, b1, b2);

  cvt_f32_bf16<<<dim3(16384), blk, 0, stream>>>(x, xb);

  // GEMM1: [16384,2048]@[2048,3072] -> out1 (cache_k|cache_v|q), 64x12 tiles
  gemm_bt<1><<<dim3(64 * 12), dim3(512), 0, stream>>>(
      xb, 2048, 1 << 30, 0, w1t, 2048, b1, out1, 3072, 2048, 12);

  // GEMM2 fused: k|v = [cache_k|cache_v]@blockdiag(Wu_k,Wu_v) -> kvb, 64x16
  gemm_bt<1><<<dim3(64 * 16), dim3(512), 0, stream>>>(
      out1, 3072, 2048, 512, w2t, 512, b2, kvb, 4096, 512, 16);

  // per-token attention
  attn_kernel<<<dim3(16384), blk, 0, stream>>>(out1, kvb, attO);

  // GEMM3: attO@Wo + bo -> d_out fp32, 64x8 tiles
  gemm_bt<0><<<dim3(64 * 8), dim3(512), 0, stream>>>(
      attO, 2048, 1 << 30, 0, w3t, 2048, bo, (float*)d_out, 2048, 2048, 8);
}